// Round 17
// baseline (25.290 us; speedup 1.0000x reference)
//
#include <hip/hip_runtime.h>
#include <math.h>

// SegmentTreeAttention — MI355X (gfx950), round 17.
// B=16, S=8192, D=64, N=32, LEVELS=5. f32 in/out. valid_lens per-batch.
//
// r13=23.9 best; r14/r15/r16 closed micro/QPB/register axes. This round:
// HALF-FAST DOTS (the r11 idea executed correctly):
//  - dL = q.(P[mid]-P[a]) stays EXACT (subtract-then-dot, ref rounding).
//  - dR = dotRA - dL, where dotRA = q.(P[r']-P[a]) is a maintained scalar
//    (exact telescoping: dotRA' = cond ? dL : dR). Halves dot work and
//    deletes the pkR register frontier (-16 VGPR; offR tracked for rescue).
//  - gray = (okR && |sL-sR| < 3e-2  [deviation bound ~1e-3, 30x margin])
//           OR r10's 1e-6 dn-band. Rescue re-reads P[r'] from LDS,
//    recomputes dR exactly, re-applies r10's exact cond logic (incl. the
//    nested div rescue) -> cond BIT-IDENTICAL to r13's validated path.
//    (r11's failure was both-dots-fast + a 1e-3 dn-band that fired ~40%
//    of wave-levels; this fires ~4%, same as r13's existing dn-band.)
// Keeps verbatim: QPB=64, 2-query ILP, DPP reduce, clamp identity,
// div-free cond, rcp weights, coef-folded gather, byte offsets, q-hoist.

#define SEG_N   32
#define DIM     64
#define LEVELS  5
#define QPB     64      // queries per block
#define THREADS 256
#define PAD     68      // LDS row stride in dwords
#define PADB    (PAD * 4)

#define DPP_QUAD_XOR1   0xB1    // quad_perm [1,0,3,2]
#define DPP_QUAD_XOR2   0x4E    // quad_perm [2,3,0,1]
#define DPP_ROW_HMIRROR 0x141   // row_half_mirror (lane p -> 7-p within 8)

#if __has_builtin(__builtin_amdgcn_rcpf)
#define RCPF(x) __builtin_amdgcn_rcpf(x)
#else
#define RCPF(x) (1.0f / (x))
#endif

template <int CTRL>
__device__ __forceinline__ float dpp_xadd(float v) {
    const int s = __builtin_amdgcn_update_dpp(0, __float_as_int(v), CTRL, 0xf, 0xf, true);
    return v + __int_as_float(s);
}

// 8-lane group sum, all lanes get the bit-identical total.
__device__ __forceinline__ float group8_sum(float v) {
    v = dpp_xadd<DPP_QUAD_XOR1>(v);
    v = dpp_xadd<DPP_QUAD_XOR2>(v);
    v = dpp_xadd<DPP_ROW_HMIRROR>(v);
    return v;
}

__device__ __forceinline__ float4 f4sub(const float4 a, const float4 b) {
    return make_float4(a.x - b.x, a.y - b.y, a.z - b.z, a.w - b.w);
}
__device__ __forceinline__ float dot4(const float4 a, const float4 b) {
    return a.x * b.x + a.y * b.y + a.z * b.z + a.w * b.w;
}
// acc += v * w
__device__ __forceinline__ void fmaw(float4& acc, const float4 v, float w) {
    acc.x = fmaf(v.x, w, acc.x);
    acc.y = fmaf(v.y, w, acc.y);
    acc.z = fmaf(v.z, w, acc.z);
    acc.w = fmaf(v.w, w, acc.w);
}

__global__ __launch_bounds__(THREADS) void segtree_attn_kernel(
    const float* __restrict__ q,
    const float* __restrict__ keys,
    const float* __restrict__ values,
    const int*   __restrict__ vlen,
    float*       __restrict__ out,
    int S)
{
    __shared__ float P[2][SEG_N * PAD];   // P[0]=Pk, P[1]=Pv

    const int b = blockIdx.y;
    const int t = threadIdx.x;
    const int g = t >> 3;           // query group within block (0..31)
    const int u = t & 7;            // lane within group
    const int c = u * 8;            // column base (2x float4)
    const int c4 = c * 4;           // byte offset of column base

    const int sA = blockIdx.x * QPB + g;
    const int sB = sA + 32;

    // ---- q loads hoisted: latency hides under staging + barrier ----
    const float* qpA = q + ((size_t)b * S + sA) * DIM + c;
    const float* qpB = q + ((size_t)b * S + sB) * DIM + c;
    const float4 qA0 = *(const float4*)qpA;
    const float4 qA1 = *(const float4*)(qpA + 4);
    const float4 qB0 = *(const float4*)qpB;
    const float4 qB1 = *(const float4*)(qpB + 4);

    // ---- Stage prefix sums into LDS: P[0]=0, P[m]=sum_{l=1..m} x[l] ----
    if (t < 2 * DIM) {
        const int col = t & (DIM - 1);
        const float* src = ((t < DIM) ? keys : values) + (size_t)b * SEG_N * DIM + col;
        float* dst = (t < DIM) ? P[0] : P[1];
        float acc = 0.0f;
        dst[col] = 0.0f;
        #pragma unroll
        for (int row = 1; row < SEG_N; ++row) {
            acc += src[row * DIM];
            dst[row * PAD + col] = acc;
        }
    }
    const int n = vlen[b];          // block-uniform (valid_lens is [B])
    __syncthreads();

    const int hnc = max(min(n - 1, SEG_N - 1), 0);
    const float scale[LEVELS] = {0.0625f, 0.125f, 0.25f, 0.5f, 1.0f};
    const char* Kb = (const char*)&P[0][0];
    const char* Vb = (const char*)&P[1][0];

    // initial frontiers: P[l-1]=P[0]=0 ; P[clamp(min(r,n-1))] = P[hnc]
    const int offN = hnc * PADB + c4;
    {   // init range-dots: dotRA = q.(P[hnc] - P[0]) = q.P[hnc] exactly
    }
    const float4 pkN0 = *(const float4*)(Kb + offN);
    const float4 pkN1 = *(const float4*)(Kb + offN + 16);
    float dotRA_A = group8_sum(dot4(qA0, pkN0) + dot4(qA1, pkN1));
    float dotRA_B = group8_sum(dot4(qB0, pkN0) + dot4(qB1, pkN1));

    float4 pkA_A0 = make_float4(0.f,0.f,0.f,0.f), pkA_A1 = make_float4(0.f,0.f,0.f,0.f);
    float4 pkA_B0 = make_float4(0.f,0.f,0.f,0.f), pkA_B1 = make_float4(0.f,0.f,0.f,0.f);

    int offA_A = c4, offR_A = offN;     // byte offsets of frontier rows
    int offA_B = c4, offR_B = offN;
    float cA_A = 0.0f, cR_A = 0.0f;     // running coefs of frontier rows
    float cA_B = 0.0f, cR_B = 0.0f;
    int midA = 16, midB = 16;
    int lA = 1, rA = SEG_N;
    int lB = 1, rB = SEG_N;

    // emissions: one finalized (row, coef) per level + 2 final frontiers
    float cE_A[LEVELS + 2], cE_B[LEVELS + 2];
    int   rowE_A[LEVELS + 2], rowE_B[LEVELS + 2];

    #pragma unroll
    for (int lev = 0; lev < LEVELS; ++lev) {
        const int step = 8 >> lev;
        const int cmA = min(midA, hnc);     // clamped row (clamp identity)
        const int cmB = min(midB, hnc);
        const int offMA = cmA * PADB + c4;
        const int offMB = cmB * PADB + c4;

        const float4 pkM_A0 = *(const float4*)(Kb + offMA);
        const float4 pkM_A1 = *(const float4*)(Kb + offMA + 16);
        const float4 pkM_B0 = *(const float4*)(Kb + offMB);
        const float4 pkM_B1 = *(const float4*)(Kb + offMB + 16);

        // dL exact: subtract-then-dot (reference rounding structure)
        float dLA = dot4(qA0, f4sub(pkM_A0, pkA_A0)) + dot4(qA1, f4sub(pkM_A1, pkA_A1));
        float dLB = dot4(qB0, f4sub(pkM_B0, pkA_B0)) + dot4(qB1, f4sub(pkM_B1, pkA_B1));
        dLA = group8_sum(dLA);
        dLB = group8_sum(dLB);

        // dR derived from maintained range-dot (deviation <= ~1e-3)
        float dRA = dotRA_A - dLA;
        float dRB = dotRA_B - dLB;

        const bool okLA = (min(midA, n - 1) >= lA);
        const bool okRA = (min(rA,   n - 1) >= midA + 1);
        const bool okLB = (min(midB, n - 1) >= lB);
        const bool okRB = (min(rB,   n - 1) >= midB + 1);

        const float sLA = okLA ? dLA : 0.0f;
        float       sRA = okRA ? dRA : 0.0f;
        const float sLB = okLB ? dLB : 0.0f;
        float       sRB = okRB ? dRB : 0.0f;

        const float dnLA = 1.0f + __expf(-sLA);
        float       dnRA = 1.0f + __expf(-sRA);
        const float dnLB = 1.0f + __expf(-sLB);
        float       dnRB = 1.0f + __expf(-sRB);

        bool condA = (dnLA <= dnRA);
        bool condB = (dnLB <= dnRB);

        // gray: fast-dR could flip cond only if |sL-sR| < ~1e-3 (30x
        // margin -> 3e-2 window), or we're in r10's dn-plateau band.
        const bool grayA = (okRA && (__builtin_fabsf(sLA - sRA) < 3e-2f)) ||
                           ((dnLA > dnRA) && (dnLA - dnRA < dnLA * 1e-6f));
        const bool grayB = (okRB && (__builtin_fabsf(sLB - sRB) < 3e-2f)) ||
                           ((dnLB > dnRB) && (dnLB - dnRB < dnLB * 1e-6f));
        if (__any(grayA || grayB)) {        // ~4% of wave-levels
            // exact dR: re-read frontier row P[r'] by tracked offset
            const float4 rAx0 = *(const float4*)(Kb + offR_A);
            const float4 rAx1 = *(const float4*)(Kb + offR_A + 16);
            const float4 rBx0 = *(const float4*)(Kb + offR_B);
            const float4 rBx1 = *(const float4*)(Kb + offR_B + 16);
            float dRxA = dot4(qA0, f4sub(rAx0, pkM_A0)) + dot4(qA1, f4sub(rAx1, pkM_A1));
            float dRxB = dot4(qB0, f4sub(rBx0, pkM_B0)) + dot4(qB1, f4sub(rBx1, pkM_B1));
            dRxA = group8_sum(dRxA);
            dRxB = group8_sum(dRxB);
            dRA = dRxA;                      // adopt exact dR (also for dotRA)
            dRB = dRxB;
            sRA = okRA ? dRA : 0.0f;
            sRB = okRB ? dRB : 0.0f;
            dnRA = 1.0f + __expf(-sRA);
            dnRB = 1.0f + __expf(-sRB);
            condA = (dnLA <= dnRA);
            condB = (dnLB <= dnRB);
            // r10's nested dn-plateau rescue (exact IEEE divs)
            const bool g2A = (dnLA > dnRA) && ((dnLA - dnRA) < dnLA * 1e-6f);
            const bool g2B = (dnLB > dnRB) && ((dnLB - dnRB) < dnLB * 1e-6f);
            if (__any(g2A || g2B)) {
                condA = ((1.0f / dnLA) >= (1.0f / dnRA));
                condB = ((1.0f / dnLB) >= (1.0f / dnRB));
            }
        }

        const bool  okselA = condA ? okRA : okLA;
        const bool  okselB = condB ? okRB : okLB;
        const float wselA  = RCPF(condA ? dnRA : dnLA);  // weight: <=1ulp
        const float wselB  = RCPF(condB ? dnRB : dnLB);
        const float wAv = okselA ? (wselA * scale[lev]) : 0.0f;  // pow2: exact
        const float wBv = okselB ? (wselB * scale[lev]) : 0.0f;

        // ---- coefficient-folded emission (static slot = lev) ----
        rowE_A[lev] = condA ? offR_A : offA_A;
        cE_A[lev]   = condA ? (cR_A + wAv) : (cA_A - wAv);
        rowE_B[lev] = condB ? offR_B : offA_B;
        cE_B[lev]   = condB ? (cR_B + wBv) : (cA_B - wBv);

        cR_A   = condA ? -wAv  : cR_A;
        cA_A   = condA ? cA_A  : wAv;
        offR_A = condA ? offMA : offR_A;
        offA_A = condA ? offA_A : offMA;
        cR_B   = condB ? -wBv  : cR_B;
        cA_B   = condB ? cA_B  : wBv;
        offR_B = condB ? offMB : offR_B;
        offA_B = condB ? offA_B : offMB;

        // range-dot telescoping: dotRA' = q.(P[r''] - P[a''])
        dotRA_A = condA ? dLA : dRA;
        dotRA_B = condB ? dLB : dRB;

        if (condA) {
            rA = midA;
        } else {
            lA = midA + 1;
            pkA_A0 = pkM_A0; pkA_A1 = pkM_A1;
        }
        if (condB) {
            rB = midB;
        } else {
            lB = midB + 1;
            pkA_B0 = pkM_B0; pkA_B1 = pkM_B1;
        }
        if (lev < LEVELS - 1) {
            midA = condA ? (midA - step) : (midA + step);
            midB = condB ? (midB - step) : (midB + step);
        }
    }

    // final frontier emissions
    rowE_A[LEVELS]     = offA_A;  cE_A[LEVELS]     = cA_A;
    rowE_A[LEVELS + 1] = offR_A;  cE_A[LEVELS + 1] = cR_A;
    rowE_B[LEVELS]     = offA_B;  cE_B[LEVELS]     = cA_B;
    rowE_B[LEVELS + 1] = offR_B;  cE_B[LEVELS + 1] = cR_B;

    // ---- folded gather: ans = sum_e coef_e * Pv[row_e]  (7 rows) ----
    float4 aA0 = make_float4(0.f,0.f,0.f,0.f), aA1 = make_float4(0.f,0.f,0.f,0.f);
    float4 aB0 = make_float4(0.f,0.f,0.f,0.f), aB1 = make_float4(0.f,0.f,0.f,0.f);
    #pragma unroll
    for (int e = 0; e < LEVELS + 2; ++e) {
        const float4 vA0 = *(const float4*)(Vb + rowE_A[e]);
        const float4 vA1 = *(const float4*)(Vb + rowE_A[e] + 16);
        fmaw(aA0, vA0, cE_A[e]);
        fmaw(aA1, vA1, cE_A[e]);
        const float4 vB0 = *(const float4*)(Vb + rowE_B[e]);
        const float4 vB1 = *(const float4*)(Vb + rowE_B[e] + 16);
        fmaw(aB0, vB0, cE_B[e]);
        fmaw(aB1, vB1, cE_B[e]);
    }

    float* opA = out + ((size_t)b * S + sA) * DIM + c;
    float* opB = out + ((size_t)b * S + sB) * DIM + c;
    *(float4*)opA       = aA0;
    *(float4*)(opA + 4) = aA1;
    *(float4*)opB       = aB0;
    *(float4*)(opB + 4) = aB1;
}

extern "C" void kernel_launch(void* const* d_in, const int* in_sizes, int n_in,
                              void* d_out, int out_size, void* d_ws, size_t ws_size,
                              hipStream_t stream) {
    const float* q    = (const float*)d_in[0];
    const float* keys = (const float*)d_in[1];
    const float* vals = (const float*)d_in[2];
    const int*   vl   = (const int*)d_in[3];
    float* out = (float*)d_out;

    const int B = in_sizes[3];                 // 16
    const int S = in_sizes[0] / (B * DIM);     // 8192

    dim3 grid(S / QPB, B);
    segtree_attn_kernel<<<grid, THREADS, 0, stream>>>(q, keys, vals, vl, out, S);
}

// Round 18
// 22.307 us; speedup vs baseline: 1.1337x; 1.1337x over previous
//
#include <hip/hip_runtime.h>
#include <math.h>

// SegmentTreeAttention — MI355X (gfx950), round 18.
// B=16, S=8192, D=64, N=32, LEVELS=5. f32 in/out. valid_lens per-batch.
//
// r13=23.9 best. All axes closed except one confounded cell: QPB=32 was
// only ever tested WITH extra state (r8 inline-Pv, r9 speculation).
// This round: r13 skeleton, SINGLE query per 8-lane group (drop the
// B-query ILP). Per-thread live state halves -> ~55-65 VGPR (r11's lean
// variant measured 56), crossing the 64-VGPR cliff: 8 waves/SIMD vs ~5.
// Staging redundancy at 4096 blocks is de-risked by r15 (halving total
// staging work was neutral -> staging is overlapped, not critical-path).
// Descent math r13 VERBATIM: exact subtract-then-dot, DPP reduce, clamp
// identity, div-free cond + 1e-6 gray rescue (bit-exact), rcp weights,
// coef-folded gather, byte offsets, q-load hoist, no launch-bounds cap.

#define SEG_N   32
#define DIM     64
#define LEVELS  5
#define QPB     32      // queries per block (1 per 8-lane group)
#define THREADS 256
#define PAD     68      // LDS row stride in dwords
#define PADB    (PAD * 4)

#define DPP_QUAD_XOR1   0xB1    // quad_perm [1,0,3,2]
#define DPP_QUAD_XOR2   0x4E    // quad_perm [2,3,0,1]
#define DPP_ROW_HMIRROR 0x141   // row_half_mirror (lane p -> 7-p within 8)

#if __has_builtin(__builtin_amdgcn_rcpf)
#define RCPF(x) __builtin_amdgcn_rcpf(x)
#else
#define RCPF(x) (1.0f / (x))
#endif

template <int CTRL>
__device__ __forceinline__ float dpp_xadd(float v) {
    const int s = __builtin_amdgcn_update_dpp(0, __float_as_int(v), CTRL, 0xf, 0xf, true);
    return v + __int_as_float(s);
}

// 8-lane group sum, all lanes get the bit-identical total.
__device__ __forceinline__ float group8_sum(float v) {
    v = dpp_xadd<DPP_QUAD_XOR1>(v);
    v = dpp_xadd<DPP_QUAD_XOR2>(v);
    v = dpp_xadd<DPP_ROW_HMIRROR>(v);
    return v;
}

__device__ __forceinline__ float4 f4sub(const float4 a, const float4 b) {
    return make_float4(a.x - b.x, a.y - b.y, a.z - b.z, a.w - b.w);
}
__device__ __forceinline__ float dot4(const float4 a, const float4 b) {
    return a.x * b.x + a.y * b.y + a.z * b.z + a.w * b.w;
}
// acc += v * w
__device__ __forceinline__ void fmaw(float4& acc, const float4 v, float w) {
    acc.x = fmaf(v.x, w, acc.x);
    acc.y = fmaf(v.y, w, acc.y);
    acc.z = fmaf(v.z, w, acc.z);
    acc.w = fmaf(v.w, w, acc.w);
}

__global__ __launch_bounds__(THREADS) void segtree_attn_kernel(
    const float* __restrict__ q,
    const float* __restrict__ keys,
    const float* __restrict__ values,
    const int*   __restrict__ vlen,
    float*       __restrict__ out,
    int S)
{
    __shared__ float P[2][SEG_N * PAD];   // P[0]=Pk, P[1]=Pv

    const int b = blockIdx.y;
    const int t = threadIdx.x;
    const int g = t >> 3;           // query group within block (0..31)
    const int u = t & 7;            // lane within group
    const int c = u * 8;            // column base (2x float4)
    const int c4 = c * 4;           // byte offset of column base

    const int s = blockIdx.x * QPB + g;

    // ---- q load hoisted: latency hides under staging + barrier ----
    const float* qp = q + ((size_t)b * S + s) * DIM + c;
    const float4 q0 = *(const float4*)qp;
    const float4 q1 = *(const float4*)(qp + 4);

    // ---- Stage prefix sums into LDS: P[0]=0, P[m]=sum_{l=1..m} x[l] ----
    if (t < 2 * DIM) {
        const int col = t & (DIM - 1);
        const float* src = ((t < DIM) ? keys : values) + (size_t)b * SEG_N * DIM + col;
        float* dst = (t < DIM) ? P[0] : P[1];
        float acc = 0.0f;
        dst[col] = 0.0f;
        #pragma unroll
        for (int row = 1; row < SEG_N; ++row) {
            acc += src[row * DIM];
            dst[row * PAD + col] = acc;
        }
    }
    const int n = vlen[b];          // block-uniform (valid_lens is [B])
    __syncthreads();

    const int hnc = max(min(n - 1, SEG_N - 1), 0);
    const float scale[LEVELS] = {0.0625f, 0.125f, 0.25f, 0.5f, 1.0f};
    const char* Kb = (const char*)&P[0][0];
    const char* Vb = (const char*)&P[1][0];

    // initial frontiers: P[l-1]=P[0]=0 ; P[clamp(min(r,n-1))] = P[hnc]
    const int offN = hnc * PADB + c4;
    float4 pkR0 = *(const float4*)(Kb + offN);
    float4 pkR1 = *(const float4*)(Kb + offN + 16);
    float4 pkA0 = make_float4(0.f,0.f,0.f,0.f), pkA1 = make_float4(0.f,0.f,0.f,0.f);

    int offA = c4, offR = offN;     // byte offsets of frontier rows
    float cA = 0.0f, cR = 0.0f;     // running coefs of frontier rows
    int mid = 16;
    int l = 1, r = SEG_N;

    // emissions: one finalized (row, coef) per level + 2 final frontiers
    float cE[LEVELS + 2];
    int   rowE[LEVELS + 2];

    #pragma unroll
    for (int lev = 0; lev < LEVELS; ++lev) {
        const int step = 8 >> lev;
        const int cm = min(mid, hnc);       // clamped row (clamp identity)
        const int offM = cm * PADB + c4;

        const float4 pkM0 = *(const float4*)(Kb + offM);
        const float4 pkM1 = *(const float4*)(Kb + offM + 16);

        // subtract-then-dot (matches reference rounding structure)
        float dL = dot4(q0, f4sub(pkM0, pkA0)) + dot4(q1, f4sub(pkM1, pkA1));
        float dR = dot4(q0, f4sub(pkR0, pkM0)) + dot4(q1, f4sub(pkR1, pkM1));

        dL = group8_sum(dL);
        dR = group8_sum(dR);

        const bool okL = (min(mid, n - 1) >= l);
        const bool okR = (min(r,   n - 1) >= mid + 1);

        const float sL = okL ? dL : 0.0f;
        const float sR = okR ? dR : 0.0f;

        // sigmoid denominators (exact, same __expf as all passing rounds)
        const float dnL = 1.0f + __expf(-sL);
        const float dnR = 1.0f + __expf(-sR);

        // div-free cond with gray rescue (r10-validated, bit-exact)
        bool cond = (dnL <= dnR);
        const bool gray = (dnL > dnR) && ((dnL - dnR) < dnL * 1e-6f);
        if (__any(gray)) {                  // P ~ 1e-5 per wave-level
            cond = ((1.0f / dnL) >= (1.0f / dnR));
        }

        const bool  oksel = cond ? okR : okL;
        const float wsel  = RCPF(cond ? dnR : dnL);  // weight: <=1ulp
        const float w = oksel ? (wsel * scale[lev]) : 0.0f;   // pow2: exact

        // ---- coefficient-folded emission (static slot = lev) ----
        rowE[lev] = cond ? offR : offA;
        cE[lev]   = cond ? (cR + w) : (cA - w);

        cR   = cond ? -w   : cR;
        cA   = cond ? cA   : w;
        offR = cond ? offM : offR;
        offA = cond ? offA : offM;

        if (cond) {
            r = mid;
            pkR0 = pkM0; pkR1 = pkM1;
        } else {
            l = mid + 1;
            pkA0 = pkM0; pkA1 = pkM1;
        }
        if (lev < LEVELS - 1) {
            mid = cond ? (mid - step) : (mid + step);
        }
    }

    // final frontier emissions
    rowE[LEVELS]     = offA;  cE[LEVELS]     = cA;
    rowE[LEVELS + 1] = offR;  cE[LEVELS + 1] = cR;

    // ---- folded gather: ans = sum_e coef_e * Pv[row_e]  (7 rows) ----
    float4 a0 = make_float4(0.f,0.f,0.f,0.f), a1 = make_float4(0.f,0.f,0.f,0.f);
    #pragma unroll
    for (int e = 0; e < LEVELS + 2; ++e) {
        const float4 v0 = *(const float4*)(Vb + rowE[e]);
        const float4 v1 = *(const float4*)(Vb + rowE[e] + 16);
        fmaw(a0, v0, cE[e]);
        fmaw(a1, v1, cE[e]);
    }

    float* op = out + ((size_t)b * S + s) * DIM + c;
    *(float4*)op       = a0;
    *(float4*)(op + 4) = a1;
}

extern "C" void kernel_launch(void* const* d_in, const int* in_sizes, int n_in,
                              void* d_out, int out_size, void* d_ws, size_t ws_size,
                              hipStream_t stream) {
    const float* q    = (const float*)d_in[0];
    const float* keys = (const float*)d_in[1];
    const float* vals = (const float*)d_in[2];
    const int*   vl   = (const int*)d_in[3];
    float* out = (float*)d_out;

    const int B = in_sizes[3];                 // 16
    const int S = in_sizes[0] / (B * DIM);     // 8192

    dim3 grid(S / QPB, B);
    segtree_attn_kernel<<<grid, THREADS, 0, stream>>>(q, keys, vals, vl, out, S);
}